// Round 10
// baseline (316.388 us; speedup 1.0000x reference)
//
#include <hip/hip_runtime.h>

typedef unsigned short ushort_t;
typedef unsigned int uint_t;

typedef __bf16 bf16x8 __attribute__((ext_vector_type(8)));
typedef float f32x4 __attribute__((ext_vector_type(4)));

#define N_NODES 50000
#define N_EDGES 800000
#define DIM 128
#define NUM_GRAPHS 512
#define LDA 136  // padded LDS row stride in bf16 elems (128+8)
#define SCAN_BLOCKS ((N_NODES + 255) / 256)  // 196

// fill bucketing: 8 dst-range groups (one per XCD via blockIdx&7 heuristic)
#define FILL_GROUPS 8
#define FILL_BUCKET ((N_NODES + FILL_GROUPS - 1) / FILL_GROUPS)  // 6250
#define FILL_CHUNK 2048
#define FILL_CHUNKS ((N_EDGES + FILL_CHUNK - 1) / FILL_CHUNK)    // 391

// prep_kernel block ranges
#define PREP_X_BLOCKS 6250            // conv_x: 1.6M uint2/ushort4 elems / 256
#define PREP_W_BLOCKS 256             // wperm: 65536 / 256
#define PREP_B_BLOCKS 196             // batch: 50000 / 256
#define PREP_TOTAL (PREP_X_BLOCKS + PREP_W_BLOCKS + PREP_B_BLOCKS + 1)

// sliced agg: 4 slice-groups of 32 dims (64 B = 1 cache line); group = blockIdx&3
// -> per-XCD feat footprint 50000 x 64 B = 3.2 MB, fits 4 MB per-XCD L2.
#define AGG_NODES_PER_BLK 16
#define AGG_CHUNKS ((N_NODES + AGG_NODES_PER_BLK - 1) / AGG_NODES_PER_BLK)  // 3125

__device__ __forceinline__ float bf2f(ushort_t u) {
    return __uint_as_float(((uint_t)u) << 16);
}
__device__ __forceinline__ ushort_t f2bf(float f) {
    uint_t u = __float_as_uint(f);
    u = (u + 0x7FFF + ((u >> 16) & 1)) >> 16;  // RNE
    return (ushort_t)u;
}
__device__ __forceinline__ bf16x8 as_bf16x8(uint4 v) {
    return __builtin_bit_cast(bf16x8, v);
}

// ---------------- zero histogram + dtype detection (merged) ----------------
__global__ void zero_detect_kernel(int* cnt, const void* xraw, const void* eiraw,
                                   int* flags) {
    int i = blockIdx.x * 256 + threadIdx.x;
    if (i < N_NODES) cnt[i] = 0;
    if (i == 0) {
        const ushort_t* u = (const ushort_t*)xraw;
        int extreme = 0;
        for (int k = 0; k < 128; ++k) {
            int e = (u[k] >> 7) & 0xFF;
            if (e >= 0xC0) extreme++;  // |x| >= 2^65: impossible for bf16 N(0,1)
        }
        flags[0] = (extreme > 8) ? 1 : 0;
        const int* p = (const int*)eiraw;
        int nonzero = 0;
        for (int k = 1; k < 64; k += 2) nonzero += (p[k] != 0);
        flags[1] = (nonzero == 0) ? 1 : 0;  // all high-halves zero => int64
    }
}

// ---------------- merged canonicalization ----------------
__global__ __launch_bounds__(256) void prep_kernel(
    const void* xraw, const void* braw,
    const void* W0, const void* W1, const void* W2, const void* W3,
    const void* pb1a, const void* pb1b, const void* pb2a, const void* pb2b,
    const void* pWfc, const void* pbfc, const int* __restrict__ flags,
    ushort_t* __restrict__ xout, ushort_t* __restrict__ wpout,
    int* __restrict__ batch32, float* __restrict__ params) {
    int b = blockIdx.x;
    int tid = threadIdx.x;
    if (b < PREP_X_BLOCKS) {
        int i = b * 256 + tid;
        if (i < N_NODES * DIM / 4) {
            if (flags[0]) {
                float4 v = ((const float4*)xraw)[i];
                ushort4 o;
                o.x = f2bf(v.x); o.y = f2bf(v.y); o.z = f2bf(v.z); o.w = f2bf(v.w);
                ((ushort4*)xout)[i] = o;
            } else {
                ((uint2*)xout)[i] = ((const uint2*)xraw)[i];
            }
        }
    } else if (b < PREP_X_BLOCKS + PREP_W_BLOCKS) {
        int gidx = (b - PREP_X_BLOCKS) * 256 + tid;  // 0..65535
        int which = gidx >> 14;
        const void* W = (which == 0) ? W0 : (which == 1) ? W1 : (which == 2) ? W2 : W3;
        int idx = gidx & 16383;
        int j = idx & 7;
        int L = (idx >> 3) & 63;
        int t = (idx >> 9) & 7;
        int s = idx >> 12;
        int k = s * 32 + (L >> 4) * 8 + j;
        int n = t * 16 + (L & 15);
        int off = k * DIM + n;
        wpout[gidx] = flags[0] ? f2bf(((const float*)W)[off]) : ((const ushort_t*)W)[off];
    } else if (b < PREP_X_BLOCKS + PREP_W_BLOCKS + PREP_B_BLOCKS) {
        int i = (b - PREP_X_BLOCKS - PREP_W_BLOCKS) * 256 + tid;
        if (i < N_NODES) {
            const int* p = (const int*)braw;
            batch32[i] = flags[1] ? p[2 * i] : p[i];
        }
    } else {
        for (int i = tid; i < 770; i += 256) {
            const void* srcp;
            int j;
            if (i < 128)      { srcp = pb1a; j = i; }
            else if (i < 256) { srcp = pb1b; j = i - 128; }
            else if (i < 384) { srcp = pb2a; j = i - 256; }
            else if (i < 512) { srcp = pb2b; j = i - 384; }
            else if (i < 768) { srcp = pWfc; j = i - 512; }
            else              { srcp = pbfc; j = i - 768; }
            params[i] = flags[0] ? ((const float*)srcp)[j] : bf2f(((const ushort_t*)srcp)[j]);
        }
    }
}

// edges -> int32 src/dst + histogram of dst (cnt must be pre-zeroed)
__global__ void conv_edges_hist_kernel(const void* eiraw, const int* __restrict__ flags,
                                       int* __restrict__ src, int* __restrict__ dsto,
                                       int* __restrict__ cnt) {
    int e = blockIdx.x * 256 + threadIdx.x;
    if (e >= N_EDGES) return;
    const int* p = (const int*)eiraw;
    int s, d;
    if (flags[1]) {
        s = p[2 * e];
        d = p[2 * (N_EDGES + e)];
    } else {
        s = p[e];
        d = p[N_EDGES + e];
    }
    src[e] = s;
    dsto[e] = d;
    atomicAdd(&cnt[d], 1);
}

// ---------------- CSR build (counting sort by dst) ----------------

__global__ __launch_bounds__(256) void scan_reduce_kernel(const int* __restrict__ cnt,
                                                          int* __restrict__ bsum) {
    __shared__ int buf[256];
    int t = threadIdx.x;
    int i = blockIdx.x * 256 + t;
    buf[t] = (i < N_NODES) ? cnt[i] : 0;
    __syncthreads();
    for (int off = 128; off > 0; off >>= 1) {
        if (t < off) buf[t] += buf[t + off];
        __syncthreads();
    }
    if (t == 0) bsum[blockIdx.x] = buf[0];
}

__global__ __launch_bounds__(256) void scan_bsum_kernel(int* __restrict__ bsum,
                                                        int* __restrict__ rp) {
    __shared__ int buf[256];
    int t = threadIdx.x;
    int v = (t < SCAN_BLOCKS) ? bsum[t] : 0;
    buf[t] = v;
    __syncthreads();
    for (int off = 1; off < 256; off <<= 1) {
        int x = (t >= off) ? buf[t - off] : 0;
        __syncthreads();
        buf[t] += x;
        __syncthreads();
    }
    if (t < SCAN_BLOCKS) bsum[t] = buf[t] - v;  // exclusive
    if (t == 255) rp[N_NODES] = buf[255];
}

__global__ __launch_bounds__(256) void scan_final_kernel(int* __restrict__ cnt,
                                                         const int* __restrict__ bsum,
                                                         int* __restrict__ rp) {
    __shared__ int buf[256];
    int t = threadIdx.x;
    int i = blockIdx.x * 256 + t;
    int v = (i < N_NODES) ? cnt[i] : 0;
    buf[t] = v;
    __syncthreads();
    for (int off = 1; off < 256; off <<= 1) {
        int x = (t >= off) ? buf[t - off] : 0;
        __syncthreads();
        buf[t] += x;
        __syncthreads();
    }
    if (i < N_NODES) {
        int r = bsum[blockIdx.x] + buf[t] - v;
        rp[i] = r;
        cnt[i] = r;
    }
}

// Bucketed CSR fill (one dst-range bucket per XCD via blockIdx&7)
__global__ __launch_bounds__(256) void fill_kernel(const int* __restrict__ src,
                                                   const int* __restrict__ dst,
                                                   int* __restrict__ cur,
                                                   int* __restrict__ csr) {
    int group = blockIdx.x & (FILL_GROUPS - 1);
    int chunk = blockIdx.x >> 3;
    int base = chunk * FILL_CHUNK;
    int lo = group * FILL_BUCKET;
    int hi = lo + FILL_BUCKET;
#pragma unroll
    for (int i = 0; i < FILL_CHUNK; i += 256) {
        int e = base + i + threadIdx.x;
        if (e < N_EDGES) {
            int d = dst[e];
            if (d >= lo && d < hi) {
                int p = atomicAdd(&cur[d], 1);
                csr[p] = src[e];
            }
        }
    }
}

// ---------------- aggregation: h[n] = feat[n] + sum_{j in in-edges} feat[src_j] ----
// XCD-sliced: slice-group g = blockIdx&3 owns dims [g*32, g*32+32) (one 64 B line
// per row). With round-robin block->XCD dispatch, each XCD's gathers touch only
// 50000 x 64 B = 3.2 MB of feat -> resident in its 4 MB L2 (vs 12.8 MB thrash).
// 16 lanes per node (uint = 2 dims each), 16 nodes per 256-thread block,
// edge loop unrolled x8. Writes are full 64 B lines (no partial-line writeback).
__global__ __launch_bounds__(256) void agg_kernel(const ushort_t* __restrict__ feat,
                                                  const int* __restrict__ rp,
                                                  const int* __restrict__ csr,
                                                  ushort_t* __restrict__ hout) {
    int g = blockIdx.x & 3;
    int chunk = blockIdx.x >> 2;
    int n = chunk * AGG_NODES_PER_BLK + (threadIdx.x >> 4);
    int l = threadIdx.x & 15;
    if (n >= N_NODES) return;
    int coloff = g * 16 + l;  // uint index within 64-uint row
    const uint_t* fp = reinterpret_cast<const uint_t*>(feat);
    uint_t v = fp[(size_t)n * 64 + coloff];
    float a0 = bf2f((ushort_t)(v & 0xffff));
    float a1 = bf2f((ushort_t)(v >> 16));
    int e0 = rp[n], e1 = rp[n + 1];
    int j = e0;
    for (; j + 8 <= e1; j += 8) {
        int s0 = csr[j],     s1 = csr[j + 1], s2 = csr[j + 2], s3 = csr[j + 3];
        int s4 = csr[j + 4], s5 = csr[j + 5], s6 = csr[j + 6], s7 = csr[j + 7];
        uint_t w0 = fp[(size_t)s0 * 64 + coloff];
        uint_t w1 = fp[(size_t)s1 * 64 + coloff];
        uint_t w2 = fp[(size_t)s2 * 64 + coloff];
        uint_t w3 = fp[(size_t)s3 * 64 + coloff];
        uint_t w4 = fp[(size_t)s4 * 64 + coloff];
        uint_t w5 = fp[(size_t)s5 * 64 + coloff];
        uint_t w6 = fp[(size_t)s6 * 64 + coloff];
        uint_t w7 = fp[(size_t)s7 * 64 + coloff];
        a0 += bf2f((ushort_t)(w0 & 0xffff)); a1 += bf2f((ushort_t)(w0 >> 16));
        a0 += bf2f((ushort_t)(w1 & 0xffff)); a1 += bf2f((ushort_t)(w1 >> 16));
        a0 += bf2f((ushort_t)(w2 & 0xffff)); a1 += bf2f((ushort_t)(w2 >> 16));
        a0 += bf2f((ushort_t)(w3 & 0xffff)); a1 += bf2f((ushort_t)(w3 >> 16));
        a0 += bf2f((ushort_t)(w4 & 0xffff)); a1 += bf2f((ushort_t)(w4 >> 16));
        a0 += bf2f((ushort_t)(w5 & 0xffff)); a1 += bf2f((ushort_t)(w5 >> 16));
        a0 += bf2f((ushort_t)(w6 & 0xffff)); a1 += bf2f((ushort_t)(w6 >> 16));
        a0 += bf2f((ushort_t)(w7 & 0xffff)); a1 += bf2f((ushort_t)(w7 >> 16));
    }
    for (; j + 4 <= e1; j += 4) {
        int s0 = csr[j], s1 = csr[j + 1], s2 = csr[j + 2], s3 = csr[j + 3];
        uint_t w0 = fp[(size_t)s0 * 64 + coloff];
        uint_t w1 = fp[(size_t)s1 * 64 + coloff];
        uint_t w2 = fp[(size_t)s2 * 64 + coloff];
        uint_t w3 = fp[(size_t)s3 * 64 + coloff];
        a0 += bf2f((ushort_t)(w0 & 0xffff)); a1 += bf2f((ushort_t)(w0 >> 16));
        a0 += bf2f((ushort_t)(w1 & 0xffff)); a1 += bf2f((ushort_t)(w1 >> 16));
        a0 += bf2f((ushort_t)(w2 & 0xffff)); a1 += bf2f((ushort_t)(w2 >> 16));
        a0 += bf2f((ushort_t)(w3 & 0xffff)); a1 += bf2f((ushort_t)(w3 >> 16));
    }
    for (; j < e1; ++j) {
        int s = csr[j];
        uint_t w = fp[(size_t)s * 64 + coloff];
        a0 += bf2f((ushort_t)(w & 0xffff)); a1 += bf2f((ushort_t)(w >> 16));
    }
    uint_t o = (uint_t)f2bf(a0) | ((uint_t)f2bf(a1) << 16);
    reinterpret_cast<uint_t*>(hout)[(size_t)n * 64 + coloff] = o;
}

// ---------------- fused MLP: hout = relu(relu(hin@Wa+ba)@Wb+bb) ----------------
__global__ __launch_bounds__(256) void mlp_kernel(const ushort_t* __restrict__ hin,
                                                  const ushort_t* __restrict__ wpA,
                                                  const float* __restrict__ ba,
                                                  const ushort_t* __restrict__ wpB,
                                                  const float* __restrict__ bb,
                                                  ushort_t* __restrict__ hout) {
    __shared__ ushort_t As[64 * LDA];
    int tid = threadIdx.x;
    int wave = tid >> 6;
    int lane = tid & 63;
    int quad = lane >> 4;
    int cl = lane & 15;
    int row0 = blockIdx.x * 64;

    bf16x8 B1[2][4], B2[2][4];
#pragma unroll
    for (int ti = 0; ti < 2; ++ti) {
        int t = 2 * wave + ti;
#pragma unroll
        for (int s = 0; s < 4; ++s) {
            B1[ti][s] = as_bf16x8(reinterpret_cast<const uint4*>(wpA)[(s * 8 + t) * 64 + lane]);
            B2[ti][s] = as_bf16x8(reinterpret_cast<const uint4*>(wpB)[(s * 8 + t) * 64 + lane]);
        }
    }

    for (int i = tid; i < 64 * 16; i += 256) {
        int r = i >> 4, c8 = i & 15;
        uint4 v = make_uint4(0u, 0u, 0u, 0u);
        int gr = row0 + r;
        if (gr < N_NODES)
            v = reinterpret_cast<const uint4*>(hin + (size_t)gr * DIM)[c8];
        *reinterpret_cast<uint4*>(&As[r * LDA + c8 * 8]) = v;
    }
    __syncthreads();

    f32x4 acc[4][2];
#pragma unroll
    for (int m = 0; m < 4; ++m)
#pragma unroll
        for (int ti = 0; ti < 2; ++ti)
#pragma unroll
            for (int r = 0; r < 4; ++r) acc[m][ti][r] = 0.f;

#pragma unroll
    for (int s = 0; s < 4; ++s) {
#pragma unroll
        for (int m = 0; m < 4; ++m) {
            bf16x8 a = *reinterpret_cast<const bf16x8*>(&As[(m * 16 + cl) * LDA + s * 32 + quad * 8]);
#pragma unroll
            for (int ti = 0; ti < 2; ++ti)
                acc[m][ti] = __builtin_amdgcn_mfma_f32_16x16x32_bf16(a, B1[ti][s], acc[m][ti], 0, 0, 0);
        }
    }
    __syncthreads();

#pragma unroll
    for (int ti = 0; ti < 2; ++ti) {
        int col = 32 * wave + ti * 16 + cl;
        float bv = ba[col];
#pragma unroll
        for (int m = 0; m < 4; ++m)
#pragma unroll
            for (int r = 0; r < 4; ++r) {
                float v = acc[m][ti][r] + bv;
                As[(m * 16 + quad * 4 + r) * LDA + col] = f2bf(fmaxf(v, 0.f));
            }
    }
    __syncthreads();

#pragma unroll
    for (int m = 0; m < 4; ++m)
#pragma unroll
        for (int ti = 0; ti < 2; ++ti)
#pragma unroll
            for (int r = 0; r < 4; ++r) acc[m][ti][r] = 0.f;

#pragma unroll
    for (int s = 0; s < 4; ++s) {
#pragma unroll
        for (int m = 0; m < 4; ++m) {
            bf16x8 a = *reinterpret_cast<const bf16x8*>(&As[(m * 16 + cl) * LDA + s * 32 + quad * 8]);
#pragma unroll
            for (int ti = 0; ti < 2; ++ti)
                acc[m][ti] = __builtin_amdgcn_mfma_f32_16x16x32_bf16(a, B2[ti][s], acc[m][ti], 0, 0, 0);
        }
    }

#pragma unroll
    for (int ti = 0; ti < 2; ++ti) {
        int col = 32 * wave + ti * 16 + cl;
        float bv = bb[col];
#pragma unroll
        for (int m = 0; m < 4; ++m)
#pragma unroll
            for (int r = 0; r < 4; ++r) {
                int gr = row0 + m * 16 + quad * 4 + r;
                if (gr < N_NODES) {
                    float v = acc[m][ti][r] + bv;
                    hout[(size_t)gr * DIM + col] = f2bf(fmaxf(v, 0.f));
                }
            }
    }
}

// ---------------- mean-pool per graph + FC(128->2) ----------------
__global__ __launch_bounds__(256) void pool_fc_kernel(const ushort_t* __restrict__ h2,
                                                      const int* __restrict__ batch,
                                                      const float* __restrict__ params,
                                                      const int* __restrict__ flags,
                                                      void* __restrict__ out) {
    int g = blockIdx.x;
    int t = threadIdx.x;
    int col = t & 63;   // uint column (dims 2*col, 2*col+1)
    int rg = t >> 6;    // row-group 0..3

    int lo = 0, hi = N_NODES;
    while (lo < hi) { int mid = (lo + hi) >> 1; if (batch[mid] < g) lo = mid + 1; else hi = mid; }
    int start = lo;
    hi = N_NODES;
    while (lo < hi) { int mid = (lo + hi) >> 1; if (batch[mid] < g + 1) lo = mid + 1; else hi = mid; }
    int end = lo;

    const uint_t* hp = reinterpret_cast<const uint_t*>(h2);  // row = 64 uints
    float a0 = 0.f, a1 = 0.f;
    int n = start + rg;
    for (; n + 4 < end; n += 8) {
        uint_t w0 = hp[(size_t)n * 64 + col];
        uint_t w1 = hp[(size_t)(n + 4) * 64 + col];
        a0 += bf2f((ushort_t)(w0 & 0xffff)); a1 += bf2f((ushort_t)(w0 >> 16));
        a0 += bf2f((ushort_t)(w1 & 0xffff)); a1 += bf2f((ushort_t)(w1 >> 16));
    }
    for (; n < end; n += 4) {
        uint_t w = hp[(size_t)n * 64 + col];
        a0 += bf2f((ushort_t)(w & 0xffff)); a1 += bf2f((ushort_t)(w >> 16));
    }

    __shared__ float s0[256], s1[256];
    s0[t] = a0; s1[t] = a1;
    __syncthreads();

    if (rg == 0) {  // threads 0..63 = wave 0
        a0 = s0[col] + s0[64 + col] + s0[128 + col] + s0[192 + col];
        a1 = s1[col] + s1[64 + col] + s1[128 + col] + s1[192 + col];
        int c = end - start;
        float inv = 1.0f / (float)(c > 0 ? c : 1);
        float m0 = a0 * inv, m1 = a1 * inv;
        int d0 = 2 * col, d1 = 2 * col + 1;
        float p0 = m0 * params[512 + d0 * 2 + 0] + m1 * params[512 + d1 * 2 + 0];
        float p1 = m0 * params[512 + d0 * 2 + 1] + m1 * params[512 + d1 * 2 + 1];
#pragma unroll
        for (int off = 32; off > 0; off >>= 1) {
            p0 += __shfl_down(p0, off, 64);
            p1 += __shfl_down(p1, off, 64);
        }
        if (col == 0) {
            float o0 = p0 + params[768];
            float o1 = p1 + params[769];
            if (flags[0]) {
                ((float*)out)[g * 2 + 0] = o0;
                ((float*)out)[g * 2 + 1] = o1;
            } else {
                ((ushort_t*)out)[g * 2 + 0] = f2bf(o0);
                ((ushort_t*)out)[g * 2 + 1] = f2bf(o1);
            }
        }
    }
}

extern "C" void kernel_launch(void* const* d_in, const int* in_sizes, int n_in,
                              void* d_out, int out_size, void* d_ws, size_t ws_size,
                              hipStream_t stream) {
    const void* x = d_in[0];
    const void* ei = d_in[1];
    const void* batch = d_in[2];
    const void* W1a = d_in[3];
    const void* b1a = d_in[4];
    const void* W1b = d_in[5];
    const void* b1b = d_in[6];
    const void* W2a = d_in[7];
    const void* b2a = d_in[8];
    const void* W2b = d_in[9];
    const void* b2b = d_in[10];
    const void* Wfc = d_in[11];
    const void* bfc = d_in[12];

    // Workspace layout (~36 MB, all chunks 16B-aligned)
    char* base = (char*)d_ws;
    ushort_t* hX = (ushort_t*)base;   base += (size_t)N_NODES * DIM * 2;   // 12.8 MB
    ushort_t* hA = (ushort_t*)base;   base += (size_t)N_NODES * DIM * 2;   // 12.8 MB
    int* src32 = (int*)base;          base += (size_t)N_EDGES * 4;
    int* dst32 = (int*)base;          base += (size_t)N_EDGES * 4;
    int* batch32 = (int*)base;        base += (size_t)N_NODES * 4;
    int* rp = (int*)base;             base += (size_t)(N_NODES + 4) * 4;
    int* cnt = (int*)base;            base += (size_t)N_NODES * 4;
    int* bsum = (int*)base;           base += 256 * 4;
    int* csr = (int*)base;            base += (size_t)N_EDGES * 4;
    ushort_t* wp = (ushort_t*)base;   base += 4 * 16384 * 2;
    float* params = (float*)base;     base += 772 * 4;
    int* flags = (int*)base;          base += 16;

    ushort_t* wpA1 = wp;
    ushort_t* wpB1 = wp + 16384;
    ushort_t* wpA2 = wp + 2 * 16384;
    ushort_t* wpB2 = wp + 3 * 16384;

    // Zero histogram + detect dtypes (merged)
    zero_detect_kernel<<<(N_NODES + 255) / 256, 256, 0, stream>>>(cnt, x, ei, flags);
    // Merged canonicalization (x, weights, batch, params)
    prep_kernel<<<PREP_TOTAL, 256, 0, stream>>>(x, batch, W1a, W1b, W2a, W2b,
                                                b1a, b1b, b2a, b2b, Wfc, bfc, flags,
                                                hX, wp, batch32, params);
    conv_edges_hist_kernel<<<(N_EDGES + 255) / 256, 256, 0, stream>>>(ei, flags, src32, dst32, cnt);

    // CSR build
    scan_reduce_kernel<<<SCAN_BLOCKS, 256, 0, stream>>>(cnt, bsum);
    scan_bsum_kernel<<<1, 256, 0, stream>>>(bsum, rp);
    scan_final_kernel<<<SCAN_BLOCKS, 256, 0, stream>>>(cnt, bsum, rp);
    fill_kernel<<<FILL_CHUNKS * FILL_GROUPS, 256, 0, stream>>>(src32, dst32, cnt, csr);

    // Layer 1: agg(hX)->hA (XCD-sliced), mlp in-place on hA
    agg_kernel<<<AGG_CHUNKS * 4, 256, 0, stream>>>(hX, rp, csr, hA);
    mlp_kernel<<<(N_NODES + 63) / 64, 256, 0, stream>>>(hA, wpA1, params + 0, wpB1, params + 128, hA);
    // Layer 2: agg(hA)->hX, mlp in-place on hX
    agg_kernel<<<AGG_CHUNKS * 4, 256, 0, stream>>>(hA, rp, csr, hX);
    mlp_kernel<<<(N_NODES + 63) / 64, 256, 0, stream>>>(hX, wpA2, params + 256, wpB2, params + 384, hX);
    // Pool + FC
    pool_fc_kernel<<<NUM_GRAPHS, 256, 0, stream>>>(hX, batch32, params, flags, d_out);
}

// Round 11
// 291.203 us; speedup vs baseline: 1.0865x; 1.0865x over previous
//
#include <hip/hip_runtime.h>

typedef unsigned short ushort_t;
typedef unsigned int uint_t;

typedef __bf16 bf16x8 __attribute__((ext_vector_type(8)));
typedef float f32x4 __attribute__((ext_vector_type(4)));

#define N_NODES 50000
#define N_EDGES 800000
#define DIM 128
#define NUM_GRAPHS 512
#define LDA 136  // padded LDS row stride in bf16 elems (128+8)
#define SCAN_BLOCKS ((N_NODES + 255) / 256)  // 196

// fill bucketing: 8 dst-range groups (one per XCD via blockIdx&7 heuristic)
#define FILL_GROUPS 8
#define FILL_BUCKET ((N_NODES + FILL_GROUPS - 1) / FILL_GROUPS)  // 6250
#define FILL_CHUNK 2048
#define FILL_CHUNKS ((N_EDGES + FILL_CHUNK - 1) / FILL_CHUNK)    // 391

// prep_kernel block ranges
#define PREP_X_BLOCKS 6250            // conv_x: 1.6M uint2/ushort4 elems / 256
#define PREP_W_BLOCKS 256             // wperm: 65536 / 256
#define PREP_B_BLOCKS 196             // batch: 50000 / 256
#define PREP_TOTAL (PREP_X_BLOCKS + PREP_W_BLOCKS + PREP_B_BLOCKS + 1)

__device__ __forceinline__ float bf2f(ushort_t u) {
    return __uint_as_float(((uint_t)u) << 16);
}
__device__ __forceinline__ ushort_t f2bf(float f) {
    uint_t u = __float_as_uint(f);
    u = (u + 0x7FFF + ((u >> 16) & 1)) >> 16;  // RNE
    return (ushort_t)u;
}
__device__ __forceinline__ bf16x8 as_bf16x8(uint4 v) {
    return __builtin_bit_cast(bf16x8, v);
}

// ---------------- zero (hist + gsum) + dtype detection (merged) ----------------
__global__ void zero_detect_kernel(int* cnt, float* gsum, const void* xraw,
                                   const void* eiraw, int* flags) {
    int i = blockIdx.x * 256 + threadIdx.x;
    if (i < N_NODES) cnt[i] = 0;
    if (i < NUM_GRAPHS * DIM) gsum[i] = 0.f;
    if (i == 0) {
        const ushort_t* u = (const ushort_t*)xraw;
        int extreme = 0;
        for (int k = 0; k < 128; ++k) {
            int e = (u[k] >> 7) & 0xFF;
            if (e >= 0xC0) extreme++;  // |x| >= 2^65: impossible for bf16 N(0,1)
        }
        flags[0] = (extreme > 8) ? 1 : 0;
        const int* p = (const int*)eiraw;
        int nonzero = 0;
        for (int k = 1; k < 64; k += 2) nonzero += (p[k] != 0);
        flags[1] = (nonzero == 0) ? 1 : 0;  // all high-halves zero => int64
    }
}

// ---------------- merged canonicalization ----------------
__global__ __launch_bounds__(256) void prep_kernel(
    const void* xraw, const void* braw,
    const void* W0, const void* W1, const void* W2, const void* W3,
    const void* pb1a, const void* pb1b, const void* pb2a, const void* pb2b,
    const void* pWfc, const void* pbfc, const int* __restrict__ flags,
    ushort_t* __restrict__ xout, ushort_t* __restrict__ wpout,
    int* __restrict__ batch32, float* __restrict__ params) {
    int b = blockIdx.x;
    int tid = threadIdx.x;
    if (b < PREP_X_BLOCKS) {
        int i = b * 256 + tid;
        if (i < N_NODES * DIM / 4) {
            if (flags[0]) {
                float4 v = ((const float4*)xraw)[i];
                ushort4 o;
                o.x = f2bf(v.x); o.y = f2bf(v.y); o.z = f2bf(v.z); o.w = f2bf(v.w);
                ((ushort4*)xout)[i] = o;
            } else {
                ((uint2*)xout)[i] = ((const uint2*)xraw)[i];
            }
        }
    } else if (b < PREP_X_BLOCKS + PREP_W_BLOCKS) {
        int gidx = (b - PREP_X_BLOCKS) * 256 + tid;  // 0..65535
        int which = gidx >> 14;
        const void* W = (which == 0) ? W0 : (which == 1) ? W1 : (which == 2) ? W2 : W3;
        int idx = gidx & 16383;
        int j = idx & 7;
        int L = (idx >> 3) & 63;
        int t = (idx >> 9) & 7;
        int s = idx >> 12;
        int k = s * 32 + (L >> 4) * 8 + j;
        int n = t * 16 + (L & 15);
        int off = k * DIM + n;
        wpout[gidx] = flags[0] ? f2bf(((const float*)W)[off]) : ((const ushort_t*)W)[off];
    } else if (b < PREP_X_BLOCKS + PREP_W_BLOCKS + PREP_B_BLOCKS) {
        int i = (b - PREP_X_BLOCKS - PREP_W_BLOCKS) * 256 + tid;
        if (i < N_NODES) {
            const int* p = (const int*)braw;
            batch32[i] = flags[1] ? p[2 * i] : p[i];
        }
    } else {
        for (int i = tid; i < 770; i += 256) {
            const void* srcp;
            int j;
            if (i < 128)      { srcp = pb1a; j = i; }
            else if (i < 256) { srcp = pb1b; j = i - 128; }
            else if (i < 384) { srcp = pb2a; j = i - 256; }
            else if (i < 512) { srcp = pb2b; j = i - 384; }
            else if (i < 768) { srcp = pWfc; j = i - 512; }
            else              { srcp = pbfc; j = i - 768; }
            params[i] = flags[0] ? ((const float*)srcp)[j] : bf2f(((const ushort_t*)srcp)[j]);
        }
    }
}

// edges -> int32 src/dst + histogram of dst (cnt must be pre-zeroed)
__global__ void conv_edges_hist_kernel(const void* eiraw, const int* __restrict__ flags,
                                       int* __restrict__ src, int* __restrict__ dsto,
                                       int* __restrict__ cnt) {
    int e = blockIdx.x * 256 + threadIdx.x;
    if (e >= N_EDGES) return;
    const int* p = (const int*)eiraw;
    int s, d;
    if (flags[1]) {
        s = p[2 * e];
        d = p[2 * (N_EDGES + e)];
    } else {
        s = p[e];
        d = p[N_EDGES + e];
    }
    src[e] = s;
    dsto[e] = d;
    atomicAdd(&cnt[d], 1);
}

// ---------------- CSR build (counting sort by dst) ----------------

__global__ __launch_bounds__(256) void scan_reduce_kernel(const int* __restrict__ cnt,
                                                          int* __restrict__ bsum) {
    __shared__ int buf[256];
    int t = threadIdx.x;
    int i = blockIdx.x * 256 + t;
    buf[t] = (i < N_NODES) ? cnt[i] : 0;
    __syncthreads();
    for (int off = 128; off > 0; off >>= 1) {
        if (t < off) buf[t] += buf[t + off];
        __syncthreads();
    }
    if (t == 0) bsum[blockIdx.x] = buf[0];
}

__global__ __launch_bounds__(256) void scan_bsum_kernel(int* __restrict__ bsum,
                                                        int* __restrict__ rp) {
    __shared__ int buf[256];
    int t = threadIdx.x;
    int v = (t < SCAN_BLOCKS) ? bsum[t] : 0;
    buf[t] = v;
    __syncthreads();
    for (int off = 1; off < 256; off <<= 1) {
        int x = (t >= off) ? buf[t - off] : 0;
        __syncthreads();
        buf[t] += x;
        __syncthreads();
    }
    if (t < SCAN_BLOCKS) bsum[t] = buf[t] - v;  // exclusive
    if (t == 255) rp[N_NODES] = buf[255];
}

__global__ __launch_bounds__(256) void scan_final_kernel(int* __restrict__ cnt,
                                                         const int* __restrict__ bsum,
                                                         int* __restrict__ rp) {
    __shared__ int buf[256];
    int t = threadIdx.x;
    int i = blockIdx.x * 256 + t;
    int v = (i < N_NODES) ? cnt[i] : 0;
    buf[t] = v;
    __syncthreads();
    for (int off = 1; off < 256; off <<= 1) {
        int x = (t >= off) ? buf[t - off] : 0;
        __syncthreads();
        buf[t] += x;
        __syncthreads();
    }
    if (i < N_NODES) {
        int r = bsum[blockIdx.x] + buf[t] - v;
        rp[i] = r;
        cnt[i] = r;
    }
}

// Bucketed CSR fill (one dst-range bucket per XCD via blockIdx&7)
__global__ __launch_bounds__(256) void fill_kernel(const int* __restrict__ src,
                                                   const int* __restrict__ dst,
                                                   int* __restrict__ cur,
                                                   int* __restrict__ csr) {
    int group = blockIdx.x & (FILL_GROUPS - 1);
    int chunk = blockIdx.x >> 3;
    int base = chunk * FILL_CHUNK;
    int lo = group * FILL_BUCKET;
    int hi = lo + FILL_BUCKET;
#pragma unroll
    for (int i = 0; i < FILL_CHUNK; i += 256) {
        int e = base + i + threadIdx.x;
        if (e < N_EDGES) {
            int d = dst[e];
            if (d >= lo && d < hi) {
                int p = atomicAdd(&cur[d], 1);
                csr[p] = src[e];
            }
        }
    }
}

// ---------------- aggregation (R8 form — at its compulsory-traffic floor) ----
// Half-wave (32 lanes) per node, uint2 (4 bf16) per lane; edge loop unrolled x8.
__global__ __launch_bounds__(256) void agg_kernel(const ushort_t* __restrict__ feat,
                                                  const int* __restrict__ rp,
                                                  const int* __restrict__ csr,
                                                  ushort_t* __restrict__ hout) {
    int n = blockIdx.x * 8 + (threadIdx.x >> 5);
    int lane = threadIdx.x & 31;
    if (n >= N_NODES) return;
    const uint2* fp = reinterpret_cast<const uint2*>(feat);  // row = 32 x uint2
    uint2 v = fp[n * 32 + lane];
    float a0 = bf2f((ushort_t)(v.x & 0xffff));
    float a1 = bf2f((ushort_t)(v.x >> 16));
    float a2 = bf2f((ushort_t)(v.y & 0xffff));
    float a3 = bf2f((ushort_t)(v.y >> 16));
    int e0 = rp[n], e1 = rp[n + 1];
    int j = e0;
    for (; j + 8 <= e1; j += 8) {
        int s0 = csr[j],     s1 = csr[j + 1], s2 = csr[j + 2], s3 = csr[j + 3];
        int s4 = csr[j + 4], s5 = csr[j + 5], s6 = csr[j + 6], s7 = csr[j + 7];
        uint2 w0 = fp[s0 * 32 + lane];
        uint2 w1 = fp[s1 * 32 + lane];
        uint2 w2 = fp[s2 * 32 + lane];
        uint2 w3 = fp[s3 * 32 + lane];
        uint2 w4 = fp[s4 * 32 + lane];
        uint2 w5 = fp[s5 * 32 + lane];
        uint2 w6 = fp[s6 * 32 + lane];
        uint2 w7 = fp[s7 * 32 + lane];
        a0 += bf2f((ushort_t)(w0.x & 0xffff)); a1 += bf2f((ushort_t)(w0.x >> 16));
        a2 += bf2f((ushort_t)(w0.y & 0xffff)); a3 += bf2f((ushort_t)(w0.y >> 16));
        a0 += bf2f((ushort_t)(w1.x & 0xffff)); a1 += bf2f((ushort_t)(w1.x >> 16));
        a2 += bf2f((ushort_t)(w1.y & 0xffff)); a3 += bf2f((ushort_t)(w1.y >> 16));
        a0 += bf2f((ushort_t)(w2.x & 0xffff)); a1 += bf2f((ushort_t)(w2.x >> 16));
        a2 += bf2f((ushort_t)(w2.y & 0xffff)); a3 += bf2f((ushort_t)(w2.y >> 16));
        a0 += bf2f((ushort_t)(w3.x & 0xffff)); a1 += bf2f((ushort_t)(w3.x >> 16));
        a2 += bf2f((ushort_t)(w3.y & 0xffff)); a3 += bf2f((ushort_t)(w3.y >> 16));
        a0 += bf2f((ushort_t)(w4.x & 0xffff)); a1 += bf2f((ushort_t)(w4.x >> 16));
        a2 += bf2f((ushort_t)(w4.y & 0xffff)); a3 += bf2f((ushort_t)(w4.y >> 16));
        a0 += bf2f((ushort_t)(w5.x & 0xffff)); a1 += bf2f((ushort_t)(w5.x >> 16));
        a2 += bf2f((ushort_t)(w5.y & 0xffff)); a3 += bf2f((ushort_t)(w5.y >> 16));
        a0 += bf2f((ushort_t)(w6.x & 0xffff)); a1 += bf2f((ushort_t)(w6.x >> 16));
        a2 += bf2f((ushort_t)(w6.y & 0xffff)); a3 += bf2f((ushort_t)(w6.y >> 16));
        a0 += bf2f((ushort_t)(w7.x & 0xffff)); a1 += bf2f((ushort_t)(w7.x >> 16));
        a2 += bf2f((ushort_t)(w7.y & 0xffff)); a3 += bf2f((ushort_t)(w7.y >> 16));
    }
    for (; j + 4 <= e1; j += 4) {
        int s0 = csr[j], s1 = csr[j + 1], s2 = csr[j + 2], s3 = csr[j + 3];
        uint2 w0 = fp[s0 * 32 + lane];
        uint2 w1 = fp[s1 * 32 + lane];
        uint2 w2 = fp[s2 * 32 + lane];
        uint2 w3 = fp[s3 * 32 + lane];
        a0 += bf2f((ushort_t)(w0.x & 0xffff)); a1 += bf2f((ushort_t)(w0.x >> 16));
        a2 += bf2f((ushort_t)(w0.y & 0xffff)); a3 += bf2f((ushort_t)(w0.y >> 16));
        a0 += bf2f((ushort_t)(w1.x & 0xffff)); a1 += bf2f((ushort_t)(w1.x >> 16));
        a2 += bf2f((ushort_t)(w1.y & 0xffff)); a3 += bf2f((ushort_t)(w1.y >> 16));
        a0 += bf2f((ushort_t)(w2.x & 0xffff)); a1 += bf2f((ushort_t)(w2.x >> 16));
        a2 += bf2f((ushort_t)(w2.y & 0xffff)); a3 += bf2f((ushort_t)(w2.y >> 16));
        a0 += bf2f((ushort_t)(w3.x & 0xffff)); a1 += bf2f((ushort_t)(w3.x >> 16));
        a2 += bf2f((ushort_t)(w3.y & 0xffff)); a3 += bf2f((ushort_t)(w3.y >> 16));
    }
    for (; j < e1; ++j) {
        int s = csr[j];
        uint2 w = fp[s * 32 + lane];
        a0 += bf2f((ushort_t)(w.x & 0xffff)); a1 += bf2f((ushort_t)(w.x >> 16));
        a2 += bf2f((ushort_t)(w.y & 0xffff)); a3 += bf2f((ushort_t)(w.y >> 16));
    }
    uint2 o;
    o.x = (uint_t)f2bf(a0) | ((uint_t)f2bf(a1) << 16);
    o.y = (uint_t)f2bf(a2) | ((uint_t)f2bf(a3) << 16);
    reinterpret_cast<uint2*>(hout)[n * 32 + lane] = o;
}

// ---------------- fused MLP layer 1: hout = relu(relu(hin@Wa+ba)@Wb+bb) --------
__global__ __launch_bounds__(256) void mlp_kernel(const ushort_t* __restrict__ hin,
                                                  const ushort_t* __restrict__ wpA,
                                                  const float* __restrict__ ba,
                                                  const ushort_t* __restrict__ wpB,
                                                  const float* __restrict__ bb,
                                                  ushort_t* __restrict__ hout) {
    __shared__ ushort_t As[64 * LDA];
    int tid = threadIdx.x;
    int wave = tid >> 6;
    int lane = tid & 63;
    int quad = lane >> 4;
    int cl = lane & 15;
    int row0 = blockIdx.x * 64;

    bf16x8 B1[2][4], B2[2][4];
#pragma unroll
    for (int ti = 0; ti < 2; ++ti) {
        int t = 2 * wave + ti;
#pragma unroll
        for (int s = 0; s < 4; ++s) {
            B1[ti][s] = as_bf16x8(reinterpret_cast<const uint4*>(wpA)[(s * 8 + t) * 64 + lane]);
            B2[ti][s] = as_bf16x8(reinterpret_cast<const uint4*>(wpB)[(s * 8 + t) * 64 + lane]);
        }
    }

    for (int i = tid; i < 64 * 16; i += 256) {
        int r = i >> 4, c8 = i & 15;
        uint4 v = make_uint4(0u, 0u, 0u, 0u);
        int gr = row0 + r;
        if (gr < N_NODES)
            v = reinterpret_cast<const uint4*>(hin + (size_t)gr * DIM)[c8];
        *reinterpret_cast<uint4*>(&As[r * LDA + c8 * 8]) = v;
    }
    __syncthreads();

    f32x4 acc[4][2];
#pragma unroll
    for (int m = 0; m < 4; ++m)
#pragma unroll
        for (int ti = 0; ti < 2; ++ti)
#pragma unroll
            for (int r = 0; r < 4; ++r) acc[m][ti][r] = 0.f;

#pragma unroll
    for (int s = 0; s < 4; ++s) {
#pragma unroll
        for (int m = 0; m < 4; ++m) {
            bf16x8 a = *reinterpret_cast<const bf16x8*>(&As[(m * 16 + cl) * LDA + s * 32 + quad * 8]);
#pragma unroll
            for (int ti = 0; ti < 2; ++ti)
                acc[m][ti] = __builtin_amdgcn_mfma_f32_16x16x32_bf16(a, B1[ti][s], acc[m][ti], 0, 0, 0);
        }
    }
    __syncthreads();

#pragma unroll
    for (int ti = 0; ti < 2; ++ti) {
        int col = 32 * wave + ti * 16 + cl;
        float bv = ba[col];
#pragma unroll
        for (int m = 0; m < 4; ++m)
#pragma unroll
            for (int r = 0; r < 4; ++r) {
                float v = acc[m][ti][r] + bv;
                As[(m * 16 + quad * 4 + r) * LDA + col] = f2bf(fmaxf(v, 0.f));
            }
    }
    __syncthreads();

#pragma unroll
    for (int m = 0; m < 4; ++m)
#pragma unroll
        for (int ti = 0; ti < 2; ++ti)
#pragma unroll
            for (int r = 0; r < 4; ++r) acc[m][ti][r] = 0.f;

#pragma unroll
    for (int s = 0; s < 4; ++s) {
#pragma unroll
        for (int m = 0; m < 4; ++m) {
            bf16x8 a = *reinterpret_cast<const bf16x8*>(&As[(m * 16 + cl) * LDA + s * 32 + quad * 8]);
#pragma unroll
            for (int ti = 0; ti < 2; ++ti)
                acc[m][ti] = __builtin_amdgcn_mfma_f32_16x16x32_bf16(a, B2[ti][s], acc[m][ti], 0, 0, 0);
        }
    }

#pragma unroll
    for (int ti = 0; ti < 2; ++ti) {
        int col = 32 * wave + ti * 16 + cl;
        float bv = bb[col];
#pragma unroll
        for (int m = 0; m < 4; ++m)
#pragma unroll
            for (int r = 0; r < 4; ++r) {
                int gr = row0 + m * 16 + quad * 4 + r;
                if (gr < N_NODES) {
                    float v = acc[m][ti][r] + bv;
                    hout[(size_t)gr * DIM + col] = f2bf(fmaxf(v, 0.f));
                }
            }
    }
}

// ---------------- fused MLP layer 2 + per-graph pooling ----------------
// Same GEMMs as mlp_kernel, but the epilogue writes bf16 outputs to LDS only and
// accumulates per-graph column sums into gsum[512][128] via fp32 atomics
// (batch sorted -> <=3 graph segments per 64-row block; ~1-2 atomics/thread).
// No global h2 write at all (nothing downstream reads it).
__global__ __launch_bounds__(256) void mlp_pool_kernel(const ushort_t* __restrict__ hin,
                                                       const ushort_t* __restrict__ wpA,
                                                       const float* __restrict__ ba,
                                                       const ushort_t* __restrict__ wpB,
                                                       const float* __restrict__ bb,
                                                       const int* __restrict__ batch32,
                                                       float* __restrict__ gsum) {
    __shared__ ushort_t As[64 * LDA];
    int tid = threadIdx.x;
    int wave = tid >> 6;
    int lane = tid & 63;
    int quad = lane >> 4;
    int cl = lane & 15;
    int row0 = blockIdx.x * 64;

    bf16x8 B1[2][4], B2[2][4];
#pragma unroll
    for (int ti = 0; ti < 2; ++ti) {
        int t = 2 * wave + ti;
#pragma unroll
        for (int s = 0; s < 4; ++s) {
            B1[ti][s] = as_bf16x8(reinterpret_cast<const uint4*>(wpA)[(s * 8 + t) * 64 + lane]);
            B2[ti][s] = as_bf16x8(reinterpret_cast<const uint4*>(wpB)[(s * 8 + t) * 64 + lane]);
        }
    }

    for (int i = tid; i < 64 * 16; i += 256) {
        int r = i >> 4, c8 = i & 15;
        uint4 v = make_uint4(0u, 0u, 0u, 0u);
        int gr = row0 + r;
        if (gr < N_NODES)
            v = reinterpret_cast<const uint4*>(hin + (size_t)gr * DIM)[c8];
        *reinterpret_cast<uint4*>(&As[r * LDA + c8 * 8]) = v;
    }
    __syncthreads();

    f32x4 acc[4][2];
#pragma unroll
    for (int m = 0; m < 4; ++m)
#pragma unroll
        for (int ti = 0; ti < 2; ++ti)
#pragma unroll
            for (int r = 0; r < 4; ++r) acc[m][ti][r] = 0.f;

#pragma unroll
    for (int s = 0; s < 4; ++s) {
#pragma unroll
        for (int m = 0; m < 4; ++m) {
            bf16x8 a = *reinterpret_cast<const bf16x8*>(&As[(m * 16 + cl) * LDA + s * 32 + quad * 8]);
#pragma unroll
            for (int ti = 0; ti < 2; ++ti)
                acc[m][ti] = __builtin_amdgcn_mfma_f32_16x16x32_bf16(a, B1[ti][s], acc[m][ti], 0, 0, 0);
        }
    }
    __syncthreads();

#pragma unroll
    for (int ti = 0; ti < 2; ++ti) {
        int col = 32 * wave + ti * 16 + cl;
        float bv = ba[col];
#pragma unroll
        for (int m = 0; m < 4; ++m)
#pragma unroll
            for (int r = 0; r < 4; ++r) {
                float v = acc[m][ti][r] + bv;
                As[(m * 16 + quad * 4 + r) * LDA + col] = f2bf(fmaxf(v, 0.f));
            }
    }
    __syncthreads();

#pragma unroll
    for (int m = 0; m < 4; ++m)
#pragma unroll
        for (int ti = 0; ti < 2; ++ti)
#pragma unroll
            for (int r = 0; r < 4; ++r) acc[m][ti][r] = 0.f;

#pragma unroll
    for (int s = 0; s < 4; ++s) {
#pragma unroll
        for (int m = 0; m < 4; ++m) {
            bf16x8 a = *reinterpret_cast<const bf16x8*>(&As[(m * 16 + cl) * LDA + s * 32 + quad * 8]);
#pragma unroll
            for (int ti = 0; ti < 2; ++ti)
                acc[m][ti] = __builtin_amdgcn_mfma_f32_16x16x32_bf16(a, B2[ti][s], acc[m][ti], 0, 0, 0);
        }
    }
    __syncthreads();  // all As reads of GEMM2 done before epilogue overwrite

    // bias+relu -> bf16 into LDS (same rounding point as the stored-h2 path)
#pragma unroll
    for (int ti = 0; ti < 2; ++ti) {
        int col = 32 * wave + ti * 16 + cl;
        float bv = bb[col];
#pragma unroll
        for (int m = 0; m < 4; ++m)
#pragma unroll
            for (int r = 0; r < 4; ++r) {
                float v = acc[m][ti][r] + bv;
                As[(m * 16 + quad * 4 + r) * LDA + col] = f2bf(fmaxf(v, 0.f));
            }
    }
    __syncthreads();

    // pooling: thread t handles col c over 32 rows; flush per graph segment
    int c = tid & 127;
    int rbase = (tid >> 7) * 32;
    float accp = 0.f;
    int curg = -1;
    for (int r = rbase; r < rbase + 32; ++r) {
        int gr = row0 + r;
        if (gr >= N_NODES) break;
        int g = batch32[gr];
        if (g != curg) {
            if (curg >= 0) atomicAdd(&gsum[curg * DIM + c], accp);
            curg = g;
            accp = 0.f;
        }
        accp += bf2f(As[r * LDA + c]);
    }
    if (curg >= 0) atomicAdd(&gsum[curg * DIM + c], accp);
}

// ---------------- final FC: out[g] = (gsum[g]/count[g]) @ Wfc + bfc ----------------
__global__ __launch_bounds__(64) void fc_kernel(const float* __restrict__ gsum,
                                                const int* __restrict__ batch,
                                                const float* __restrict__ params,
                                                const int* __restrict__ flags,
                                                void* __restrict__ out) {
    int g = blockIdx.x;
    int l = threadIdx.x;
    int lo = 0, hi = N_NODES;
    while (lo < hi) { int mid = (lo + hi) >> 1; if (batch[mid] < g) lo = mid + 1; else hi = mid; }
    int start = lo;
    hi = N_NODES;
    while (lo < hi) { int mid = (lo + hi) >> 1; if (batch[mid] < g + 1) lo = mid + 1; else hi = mid; }
    int cnt = lo - start;
    float inv = 1.0f / (float)(cnt > 0 ? cnt : 1);
    float m0 = gsum[g * DIM + l] * inv;
    float m1 = gsum[g * DIM + 64 + l] * inv;
    float p0 = m0 * params[512 + l * 2 + 0] + m1 * params[512 + (64 + l) * 2 + 0];
    float p1 = m0 * params[512 + l * 2 + 1] + m1 * params[512 + (64 + l) * 2 + 1];
#pragma unroll
    for (int off = 32; off > 0; off >>= 1) {
        p0 += __shfl_down(p0, off, 64);
        p1 += __shfl_down(p1, off, 64);
    }
    if (l == 0) {
        float o0 = p0 + params[768];
        float o1 = p1 + params[769];
        if (flags[0]) {
            ((float*)out)[g * 2 + 0] = o0;
            ((float*)out)[g * 2 + 1] = o1;
        } else {
            ((ushort_t*)out)[g * 2 + 0] = f2bf(o0);
            ((ushort_t*)out)[g * 2 + 1] = f2bf(o1);
        }
    }
}

extern "C" void kernel_launch(void* const* d_in, const int* in_sizes, int n_in,
                              void* d_out, int out_size, void* d_ws, size_t ws_size,
                              hipStream_t stream) {
    const void* x = d_in[0];
    const void* ei = d_in[1];
    const void* batch = d_in[2];
    const void* W1a = d_in[3];
    const void* b1a = d_in[4];
    const void* W1b = d_in[5];
    const void* b1b = d_in[6];
    const void* W2a = d_in[7];
    const void* b2a = d_in[8];
    const void* W2b = d_in[9];
    const void* b2b = d_in[10];
    const void* Wfc = d_in[11];
    const void* bfc = d_in[12];

    // Workspace layout (~36 MB, all chunks 16B-aligned)
    char* base = (char*)d_ws;
    ushort_t* hX = (ushort_t*)base;   base += (size_t)N_NODES * DIM * 2;   // 12.8 MB
    ushort_t* hA = (ushort_t*)base;   base += (size_t)N_NODES * DIM * 2;   // 12.8 MB
    int* src32 = (int*)base;          base += (size_t)N_EDGES * 4;
    int* dst32 = (int*)base;          base += (size_t)N_EDGES * 4;
    int* batch32 = (int*)base;        base += (size_t)N_NODES * 4;
    int* rp = (int*)base;             base += (size_t)(N_NODES + 4) * 4;
    int* cnt = (int*)base;            base += (size_t)N_NODES * 4;
    int* bsum = (int*)base;           base += 256 * 4;
    int* csr = (int*)base;            base += (size_t)N_EDGES * 4;
    ushort_t* wp = (ushort_t*)base;   base += 4 * 16384 * 2;
    float* params = (float*)base;     base += 772 * 4;
    float* gsum = (float*)base;       base += (size_t)NUM_GRAPHS * DIM * 4;  // 256 KB
    int* flags = (int*)base;          base += 16;

    ushort_t* wpA1 = wp;
    ushort_t* wpB1 = wp + 16384;
    ushort_t* wpA2 = wp + 2 * 16384;
    ushort_t* wpB2 = wp + 3 * 16384;

    // Zero hist+gsum, detect dtypes (merged); 256 blocks covers 65536 threads
    zero_detect_kernel<<<256, 256, 0, stream>>>(cnt, gsum, x, ei, flags);
    // Merged canonicalization (x, weights, batch, params)
    prep_kernel<<<PREP_TOTAL, 256, 0, stream>>>(x, batch, W1a, W1b, W2a, W2b,
                                                b1a, b1b, b2a, b2b, Wfc, bfc, flags,
                                                hX, wp, batch32, params);
    conv_edges_hist_kernel<<<(N_EDGES + 255) / 256, 256, 0, stream>>>(ei, flags, src32, dst32, cnt);

    // CSR build
    scan_reduce_kernel<<<SCAN_BLOCKS, 256, 0, stream>>>(cnt, bsum);
    scan_bsum_kernel<<<1, 256, 0, stream>>>(bsum, rp);
    scan_final_kernel<<<SCAN_BLOCKS, 256, 0, stream>>>(cnt, bsum, rp);
    fill_kernel<<<FILL_CHUNKS * FILL_GROUPS, 256, 0, stream>>>(src32, dst32, cnt, csr);

    // Layer 1: agg(hX)->hA, mlp in-place on hA
    agg_kernel<<<(N_NODES + 7) / 8, 256, 0, stream>>>(hX, rp, csr, hA);
    mlp_kernel<<<(N_NODES + 63) / 64, 256, 0, stream>>>(hA, wpA1, params + 0, wpB1, params + 128, hA);
    // Layer 2: agg(hA)->hX, then MLP+pool fused (no h2 global write)
    agg_kernel<<<(N_NODES + 7) / 8, 256, 0, stream>>>(hA, rp, csr, hX);
    mlp_pool_kernel<<<(N_NODES + 63) / 64, 256, 0, stream>>>(hX, wpA2, params + 256, wpB2, params + 384,
                                                             batch32, gsum);
    // Final FC from pooled sums
    fc_kernel<<<NUM_GRAPHS, 64, 0, stream>>>(gsum, batch32, params, flags, d_out);
}

// Round 13
// 290.770 us; speedup vs baseline: 1.0881x; 1.0015x over previous
//
#include <hip/hip_runtime.h>

typedef unsigned short ushort_t;
typedef unsigned int uint_t;

typedef __bf16 bf16x8 __attribute__((ext_vector_type(8)));
typedef float f32x4 __attribute__((ext_vector_type(4)));

#define N_NODES 50000
#define N_EDGES 800000
#define DIM 128
#define NUM_GRAPHS 512
#define LDA 136  // padded LDS row stride in bf16 elems (128+8)
#define SCAN_BLOCKS ((N_NODES + 255) / 256)  // 196

// fill bucketing: 8 dst-range groups (one per XCD via blockIdx&7 heuristic)
#define FILL_GROUPS 8
#define FILL_BUCKET ((N_NODES + FILL_GROUPS - 1) / FILL_GROUPS)  // 6250
#define FILL_CHUNK 2048
#define FILL_CHUNKS ((N_EDGES + FILL_CHUNK - 1) / FILL_CHUNK)    // 391

// prep_kernel block ranges
#define PREP_X_BLOCKS 6250            // conv_x: 1.6M uint2/ushort4 elems / 256
#define PREP_W_BLOCKS 256             // wperm: 65536 / 256
#define PREP_B_BLOCKS 196             // batch: 50000 / 256
#define PREP_TOTAL (PREP_X_BLOCKS + PREP_W_BLOCKS + PREP_B_BLOCKS + 1)

__device__ __forceinline__ float bf2f(ushort_t u) {
    return __uint_as_float(((uint_t)u) << 16);
}
__device__ __forceinline__ ushort_t f2bf(float f) {
    uint_t u = __float_as_uint(f);
    u = (u + 0x7FFF + ((u >> 16) & 1)) >> 16;  // RNE
    return (ushort_t)u;
}
__device__ __forceinline__ bf16x8 as_bf16x8(uint4 v) {
    return __builtin_bit_cast(bf16x8, v);
}

// ---------------- zero (hist + gsum) + dtype detection (merged) ----------------
__global__ void zero_detect_kernel(int* cnt, float* gsum, const void* xraw,
                                   const void* eiraw, int* flags) {
    int i = blockIdx.x * 256 + threadIdx.x;
    if (i < N_NODES) cnt[i] = 0;
    if (i < NUM_GRAPHS * DIM) gsum[i] = 0.f;
    if (i == 0) {
        const ushort_t* u = (const ushort_t*)xraw;
        int extreme = 0;
        for (int k = 0; k < 128; ++k) {
            int e = (u[k] >> 7) & 0xFF;
            if (e >= 0xC0) extreme++;  // |x| >= 2^65: impossible for bf16 N(0,1)
        }
        flags[0] = (extreme > 8) ? 1 : 0;
        const int* p = (const int*)eiraw;
        int nonzero = 0;
        for (int k = 1; k < 64; k += 2) nonzero += (p[k] != 0);
        flags[1] = (nonzero == 0) ? 1 : 0;  // all high-halves zero => int64
    }
}

// ---------------- merged canonicalization ----------------
__global__ __launch_bounds__(256) void prep_kernel(
    const void* xraw, const void* braw,
    const void* W0, const void* W1, const void* W2, const void* W3,
    const void* pb1a, const void* pb1b, const void* pb2a, const void* pb2b,
    const void* pWfc, const void* pbfc, const int* __restrict__ flags,
    ushort_t* __restrict__ xout, ushort_t* __restrict__ wpout,
    int* __restrict__ batch32, float* __restrict__ params) {
    int b = blockIdx.x;
    int tid = threadIdx.x;
    if (b < PREP_X_BLOCKS) {
        int i = b * 256 + tid;
        if (i < N_NODES * DIM / 4) {
            if (flags[0]) {
                float4 v = ((const float4*)xraw)[i];
                ushort4 o;
                o.x = f2bf(v.x); o.y = f2bf(v.y); o.z = f2bf(v.z); o.w = f2bf(v.w);
                ((ushort4*)xout)[i] = o;
            } else {
                ((uint2*)xout)[i] = ((const uint2*)xraw)[i];
            }
        }
    } else if (b < PREP_X_BLOCKS + PREP_W_BLOCKS) {
        int gidx = (b - PREP_X_BLOCKS) * 256 + tid;  // 0..65535
        int which = gidx >> 14;
        const void* W = (which == 0) ? W0 : (which == 1) ? W1 : (which == 2) ? W2 : W3;
        int idx = gidx & 16383;
        int j = idx & 7;
        int L = (idx >> 3) & 63;
        int t = (idx >> 9) & 7;
        int s = idx >> 12;
        int k = s * 32 + (L >> 4) * 8 + j;
        int n = t * 16 + (L & 15);
        int off = k * DIM + n;
        wpout[gidx] = flags[0] ? f2bf(((const float*)W)[off]) : ((const ushort_t*)W)[off];
    } else if (b < PREP_X_BLOCKS + PREP_W_BLOCKS + PREP_B_BLOCKS) {
        int i = (b - PREP_X_BLOCKS - PREP_W_BLOCKS) * 256 + tid;
        if (i < N_NODES) {
            const int* p = (const int*)braw;
            batch32[i] = flags[1] ? p[2 * i] : p[i];
        }
    } else {
        for (int i = tid; i < 770; i += 256) {
            const void* srcp;
            int j;
            if (i < 128)      { srcp = pb1a; j = i; }
            else if (i < 256) { srcp = pb1b; j = i - 128; }
            else if (i < 384) { srcp = pb2a; j = i - 256; }
            else if (i < 512) { srcp = pb2b; j = i - 384; }
            else if (i < 768) { srcp = pWfc; j = i - 512; }
            else              { srcp = pbfc; j = i - 768; }
            params[i] = flags[0] ? ((const float*)srcp)[j] : bf2f(((const ushort_t*)srcp)[j]);
        }
    }
}

// edges -> int32 src/dst + histogram of dst (cnt must be pre-zeroed)
__global__ void conv_edges_hist_kernel(const void* eiraw, const int* __restrict__ flags,
                                       int* __restrict__ src, int* __restrict__ dsto,
                                       int* __restrict__ cnt) {
    int e = blockIdx.x * 256 + threadIdx.x;
    if (e >= N_EDGES) return;
    const int* p = (const int*)eiraw;
    int s, d;
    if (flags[1]) {
        s = p[2 * e];
        d = p[2 * (N_EDGES + e)];
    } else {
        s = p[e];
        d = p[N_EDGES + e];
    }
    src[e] = s;
    dsto[e] = d;
    atomicAdd(&cnt[d], 1);
}

// ---------------- CSR build (counting sort by dst) ----------------

__global__ __launch_bounds__(256) void scan_reduce_kernel(const int* __restrict__ cnt,
                                                          int* __restrict__ bsum) {
    __shared__ int buf[256];
    int t = threadIdx.x;
    int i = blockIdx.x * 256 + t;
    buf[t] = (i < N_NODES) ? cnt[i] : 0;
    __syncthreads();
    for (int off = 128; off > 0; off >>= 1) {
        if (t < off) buf[t] += buf[t + off];
        __syncthreads();
    }
    if (t == 0) bsum[blockIdx.x] = buf[0];
}

__global__ __launch_bounds__(256) void scan_bsum_kernel(int* __restrict__ bsum,
                                                        int* __restrict__ rp) {
    __shared__ int buf[256];
    int t = threadIdx.x;
    int v = (t < SCAN_BLOCKS) ? bsum[t] : 0;
    buf[t] = v;
    __syncthreads();
    for (int off = 1; off < 256; off <<= 1) {
        int x = (t >= off) ? buf[t - off] : 0;
        __syncthreads();
        buf[t] += x;
        __syncthreads();
    }
    if (t < SCAN_BLOCKS) bsum[t] = buf[t] - v;  // exclusive
    if (t == 255) rp[N_NODES] = buf[255];
}

__global__ __launch_bounds__(256) void scan_final_kernel(int* __restrict__ cnt,
                                                         const int* __restrict__ bsum,
                                                         int* __restrict__ rp) {
    __shared__ int buf[256];
    int t = threadIdx.x;
    int i = blockIdx.x * 256 + t;
    int v = (i < N_NODES) ? cnt[i] : 0;
    buf[t] = v;
    __syncthreads();
    for (int off = 1; off < 256; off <<= 1) {
        int x = (t >= off) ? buf[t - off] : 0;
        __syncthreads();
        buf[t] += x;
        __syncthreads();
    }
    if (i < N_NODES) {
        int r = bsum[blockIdx.x] + buf[t] - v;
        rp[i] = r;
        cnt[i] = r;
    }
}

// Bucketed CSR fill (one dst-range bucket per XCD via blockIdx&7)
__global__ __launch_bounds__(256) void fill_kernel(const int* __restrict__ src,
                                                   const int* __restrict__ dst,
                                                   int* __restrict__ cur,
                                                   int* __restrict__ csr) {
    int group = blockIdx.x & (FILL_GROUPS - 1);
    int chunk = blockIdx.x >> 3;
    int base = chunk * FILL_CHUNK;
    int lo = group * FILL_BUCKET;
    int hi = lo + FILL_BUCKET;
#pragma unroll
    for (int i = 0; i < FILL_CHUNK; i += 256) {
        int e = base + i + threadIdx.x;
        if (e < N_EDGES) {
            int d = dst[e];
            if (d >= lo && d < hi) {
                int p = atomicAdd(&cur[d], 1);
                csr[p] = src[e];
            }
        }
    }
}

// ---------------- aggregation: h[n] = feat[n] + sum_{j in in-edges} feat[src_j] ----
// Quarter-wave (16 lanes) per node, uint4 (8 bf16) per lane: 1 VMEM instr per
// lane per edge (was 2 with uint2) and 4 nodes/wave x unroll-8 = 32 gathers in
// flight per wave (was 16). Same per-dim summation order -> bit-identical output.
__global__ __launch_bounds__(256) void agg_kernel(const ushort_t* __restrict__ feat,
                                                  const int* __restrict__ rp,
                                                  const int* __restrict__ csr,
                                                  ushort_t* __restrict__ hout) {
    int n = blockIdx.x * 16 + (threadIdx.x >> 4);
    int lane = threadIdx.x & 15;
    if (n >= N_NODES) return;
    const uint4* fp = reinterpret_cast<const uint4*>(feat);  // row = 16 x uint4
    uint4 v = fp[(size_t)n * 16 + lane];
    float a0 = bf2f((ushort_t)(v.x & 0xffff));
    float a1 = bf2f((ushort_t)(v.x >> 16));
    float a2 = bf2f((ushort_t)(v.y & 0xffff));
    float a3 = bf2f((ushort_t)(v.y >> 16));
    float a4 = bf2f((ushort_t)(v.z & 0xffff));
    float a5 = bf2f((ushort_t)(v.z >> 16));
    float a6 = bf2f((ushort_t)(v.w & 0xffff));
    float a7 = bf2f((ushort_t)(v.w >> 16));
    int e0 = rp[n], e1 = rp[n + 1];
    int j = e0;
#define ACC8(V) \
    a0 += bf2f((ushort_t)((V).x & 0xffff)); a1 += bf2f((ushort_t)((V).x >> 16)); \
    a2 += bf2f((ushort_t)((V).y & 0xffff)); a3 += bf2f((ushort_t)((V).y >> 16)); \
    a4 += bf2f((ushort_t)((V).z & 0xffff)); a5 += bf2f((ushort_t)((V).z >> 16)); \
    a6 += bf2f((ushort_t)((V).w & 0xffff)); a7 += bf2f((ushort_t)((V).w >> 16));
    for (; j + 8 <= e1; j += 8) {
        int s0 = csr[j],     s1 = csr[j + 1], s2 = csr[j + 2], s3 = csr[j + 3];
        int s4 = csr[j + 4], s5 = csr[j + 5], s6 = csr[j + 6], s7 = csr[j + 7];
        uint4 g0 = fp[(size_t)s0 * 16 + lane];
        uint4 g1 = fp[(size_t)s1 * 16 + lane];
        uint4 g2 = fp[(size_t)s2 * 16 + lane];
        uint4 g3 = fp[(size_t)s3 * 16 + lane];
        uint4 g4 = fp[(size_t)s4 * 16 + lane];
        uint4 g5 = fp[(size_t)s5 * 16 + lane];
        uint4 g6 = fp[(size_t)s6 * 16 + lane];
        uint4 g7 = fp[(size_t)s7 * 16 + lane];
        ACC8(g0) ACC8(g1) ACC8(g2) ACC8(g3)
        ACC8(g4) ACC8(g5) ACC8(g6) ACC8(g7)
    }
    for (; j + 4 <= e1; j += 4) {
        int s0 = csr[j], s1 = csr[j + 1], s2 = csr[j + 2], s3 = csr[j + 3];
        uint4 g0 = fp[(size_t)s0 * 16 + lane];
        uint4 g1 = fp[(size_t)s1 * 16 + lane];
        uint4 g2 = fp[(size_t)s2 * 16 + lane];
        uint4 g3 = fp[(size_t)s3 * 16 + lane];
        ACC8(g0) ACC8(g1) ACC8(g2) ACC8(g3)
    }
    for (; j < e1; ++j) {
        int s = csr[j];
        uint4 g0 = fp[(size_t)s * 16 + lane];
        ACC8(g0)
    }
#undef ACC8
    uint4 o;
    o.x = (uint_t)f2bf(a0) | ((uint_t)f2bf(a1) << 16);
    o.y = (uint_t)f2bf(a2) | ((uint_t)f2bf(a3) << 16);
    o.z = (uint_t)f2bf(a4) | ((uint_t)f2bf(a5) << 16);
    o.w = (uint_t)f2bf(a6) | ((uint_t)f2bf(a7) << 16);
    reinterpret_cast<uint4*>(hout)[(size_t)n * 16 + lane] = o;
}

// ---------------- fused MLP layer 1: hout = relu(relu(hin@Wa+ba)@Wb+bb) --------
__global__ __launch_bounds__(256) void mlp_kernel(const ushort_t* __restrict__ hin,
                                                  const ushort_t* __restrict__ wpA,
                                                  const float* __restrict__ ba,
                                                  const ushort_t* __restrict__ wpB,
                                                  const float* __restrict__ bb,
                                                  ushort_t* __restrict__ hout) {
    __shared__ ushort_t As[64 * LDA];
    int tid = threadIdx.x;
    int wave = tid >> 6;
    int lane = tid & 63;
    int quad = lane >> 4;
    int cl = lane & 15;
    int row0 = blockIdx.x * 64;

    bf16x8 B1[2][4], B2[2][4];
#pragma unroll
    for (int ti = 0; ti < 2; ++ti) {
        int t = 2 * wave + ti;
#pragma unroll
        for (int s = 0; s < 4; ++s) {
            B1[ti][s] = as_bf16x8(reinterpret_cast<const uint4*>(wpA)[(s * 8 + t) * 64 + lane]);
            B2[ti][s] = as_bf16x8(reinterpret_cast<const uint4*>(wpB)[(s * 8 + t) * 64 + lane]);
        }
    }

    for (int i = tid; i < 64 * 16; i += 256) {
        int r = i >> 4, c8 = i & 15;
        uint4 v = make_uint4(0u, 0u, 0u, 0u);
        int gr = row0 + r;
        if (gr < N_NODES)
            v = reinterpret_cast<const uint4*>(hin + (size_t)gr * DIM)[c8];
        *reinterpret_cast<uint4*>(&As[r * LDA + c8 * 8]) = v;
    }
    __syncthreads();

    f32x4 acc[4][2];
#pragma unroll
    for (int m = 0; m < 4; ++m)
#pragma unroll
        for (int ti = 0; ti < 2; ++ti)
#pragma unroll
            for (int r = 0; r < 4; ++r) acc[m][ti][r] = 0.f;

#pragma unroll
    for (int s = 0; s < 4; ++s) {
#pragma unroll
        for (int m = 0; m < 4; ++m) {
            bf16x8 a = *reinterpret_cast<const bf16x8*>(&As[(m * 16 + cl) * LDA + s * 32 + quad * 8]);
#pragma unroll
            for (int ti = 0; ti < 2; ++ti)
                acc[m][ti] = __builtin_amdgcn_mfma_f32_16x16x32_bf16(a, B1[ti][s], acc[m][ti], 0, 0, 0);
        }
    }
    __syncthreads();

#pragma unroll
    for (int ti = 0; ti < 2; ++ti) {
        int col = 32 * wave + ti * 16 + cl;
        float bv = ba[col];
#pragma unroll
        for (int m = 0; m < 4; ++m)
#pragma unroll
            for (int r = 0; r < 4; ++r) {
                float v = acc[m][ti][r] + bv;
                As[(m * 16 + quad * 4 + r) * LDA + col] = f2bf(fmaxf(v, 0.f));
            }
    }
    __syncthreads();

#pragma unroll
    for (int m = 0; m < 4; ++m)
#pragma unroll
        for (int ti = 0; ti < 2; ++ti)
#pragma unroll
            for (int r = 0; r < 4; ++r) acc[m][ti][r] = 0.f;

#pragma unroll
    for (int s = 0; s < 4; ++s) {
#pragma unroll
        for (int m = 0; m < 4; ++m) {
            bf16x8 a = *reinterpret_cast<const bf16x8*>(&As[(m * 16 + cl) * LDA + s * 32 + quad * 8]);
#pragma unroll
            for (int ti = 0; ti < 2; ++ti)
                acc[m][ti] = __builtin_amdgcn_mfma_f32_16x16x32_bf16(a, B2[ti][s], acc[m][ti], 0, 0, 0);
        }
    }

#pragma unroll
    for (int ti = 0; ti < 2; ++ti) {
        int col = 32 * wave + ti * 16 + cl;
        float bv = bb[col];
#pragma unroll
        for (int m = 0; m < 4; ++m)
#pragma unroll
            for (int r = 0; r < 4; ++r) {
                int gr = row0 + m * 16 + quad * 4 + r;
                if (gr < N_NODES) {
                    float v = acc[m][ti][r] + bv;
                    hout[(size_t)gr * DIM + col] = f2bf(fmaxf(v, 0.f));
                }
            }
    }
}

// ---------------- fused MLP layer 2 + per-graph pooling ----------------
__global__ __launch_bounds__(256) void mlp_pool_kernel(const ushort_t* __restrict__ hin,
                                                       const ushort_t* __restrict__ wpA,
                                                       const float* __restrict__ ba,
                                                       const ushort_t* __restrict__ wpB,
                                                       const float* __restrict__ bb,
                                                       const int* __restrict__ batch32,
                                                       float* __restrict__ gsum) {
    __shared__ ushort_t As[64 * LDA];
    int tid = threadIdx.x;
    int wave = tid >> 6;
    int lane = tid & 63;
    int quad = lane >> 4;
    int cl = lane & 15;
    int row0 = blockIdx.x * 64;

    bf16x8 B1[2][4], B2[2][4];
#pragma unroll
    for (int ti = 0; ti < 2; ++ti) {
        int t = 2 * wave + ti;
#pragma unroll
        for (int s = 0; s < 4; ++s) {
            B1[ti][s] = as_bf16x8(reinterpret_cast<const uint4*>(wpA)[(s * 8 + t) * 64 + lane]);
            B2[ti][s] = as_bf16x8(reinterpret_cast<const uint4*>(wpB)[(s * 8 + t) * 64 + lane]);
        }
    }

    for (int i = tid; i < 64 * 16; i += 256) {
        int r = i >> 4, c8 = i & 15;
        uint4 v = make_uint4(0u, 0u, 0u, 0u);
        int gr = row0 + r;
        if (gr < N_NODES)
            v = reinterpret_cast<const uint4*>(hin + (size_t)gr * DIM)[c8];
        *reinterpret_cast<uint4*>(&As[r * LDA + c8 * 8]) = v;
    }
    __syncthreads();

    f32x4 acc[4][2];
#pragma unroll
    for (int m = 0; m < 4; ++m)
#pragma unroll
        for (int ti = 0; ti < 2; ++ti)
#pragma unroll
            for (int r = 0; r < 4; ++r) acc[m][ti][r] = 0.f;

#pragma unroll
    for (int s = 0; s < 4; ++s) {
#pragma unroll
        for (int m = 0; m < 4; ++m) {
            bf16x8 a = *reinterpret_cast<const bf16x8*>(&As[(m * 16 + cl) * LDA + s * 32 + quad * 8]);
#pragma unroll
            for (int ti = 0; ti < 2; ++ti)
                acc[m][ti] = __builtin_amdgcn_mfma_f32_16x16x32_bf16(a, B1[ti][s], acc[m][ti], 0, 0, 0);
        }
    }
    __syncthreads();

#pragma unroll
    for (int ti = 0; ti < 2; ++ti) {
        int col = 32 * wave + ti * 16 + cl;
        float bv = ba[col];
#pragma unroll
        for (int m = 0; m < 4; ++m)
#pragma unroll
            for (int r = 0; r < 4; ++r) {
                float v = acc[m][ti][r] + bv;
                As[(m * 16 + quad * 4 + r) * LDA + col] = f2bf(fmaxf(v, 0.f));
            }
    }
    __syncthreads();

#pragma unroll
    for (int m = 0; m < 4; ++m)
#pragma unroll
        for (int ti = 0; ti < 2; ++ti)
#pragma unroll
            for (int r = 0; r < 4; ++r) acc[m][ti][r] = 0.f;

#pragma unroll
    for (int s = 0; s < 4; ++s) {
#pragma unroll
        for (int m = 0; m < 4; ++m) {
            bf16x8 a = *reinterpret_cast<const bf16x8*>(&As[(m * 16 + cl) * LDA + s * 32 + quad * 8]);
#pragma unroll
            for (int ti = 0; ti < 2; ++ti)
                acc[m][ti] = __builtin_amdgcn_mfma_f32_16x16x32_bf16(a, B2[ti][s], acc[m][ti], 0, 0, 0);
        }
    }
    __syncthreads();  // all As reads of GEMM2 done before epilogue overwrite

#pragma unroll
    for (int ti = 0; ti < 2; ++ti) {
        int col = 32 * wave + ti * 16 + cl;
        float bv = bb[col];
#pragma unroll
        for (int m = 0; m < 4; ++m)
#pragma unroll
            for (int r = 0; r < 4; ++r) {
                float v = acc[m][ti][r] + bv;
                As[(m * 16 + quad * 4 + r) * LDA + col] = f2bf(fmaxf(v, 0.f));
            }
    }
    __syncthreads();

    // pooling: thread t handles col c over 32 rows; flush per graph segment
    int c = tid & 127;
    int rbase = (tid >> 7) * 32;
    float accp = 0.f;
    int curg = -1;
    for (int r = rbase; r < rbase + 32; ++r) {
        int gr = row0 + r;
        if (gr >= N_NODES) break;
        int g = batch32[gr];
        if (g != curg) {
            if (curg >= 0) atomicAdd(&gsum[curg * DIM + c], accp);
            curg = g;
            accp = 0.f;
        }
        accp += bf2f(As[r * LDA + c]);
    }
    if (curg >= 0) atomicAdd(&gsum[curg * DIM + c], accp);
}

// ---------------- final FC: out[g] = (gsum[g]/count[g]) @ Wfc + bfc ----------------
__global__ __launch_bounds__(64) void fc_kernel(const float* __restrict__ gsum,
                                                const int* __restrict__ batch,
                                                const float* __restrict__ params,
                                                const int* __restrict__ flags,
                                                void* __restrict__ out) {
    int g = blockIdx.x;
    int l = threadIdx.x;
    int lo = 0, hi = N_NODES;
    while (lo < hi) { int mid = (lo + hi) >> 1; if (batch[mid] < g) lo = mid + 1; else hi = mid; }
    int start = lo;
    hi = N_NODES;
    while (lo < hi) { int mid = (lo + hi) >> 1; if (batch[mid] < g + 1) lo = mid + 1; else hi = mid; }
    int cnt = lo - start;
    float inv = 1.0f / (float)(cnt > 0 ? cnt : 1);
    float m0 = gsum[g * DIM + l] * inv;
    float m1 = gsum[g * DIM + 64 + l] * inv;
    float p0 = m0 * params[512 + l * 2 + 0] + m1 * params[512 + (64 + l) * 2 + 0];
    float p1 = m0 * params[512 + l * 2 + 1] + m1 * params[512 + (64 + l) * 2 + 1];
#pragma unroll
    for (int off = 32; off > 0; off >>= 1) {
        p0 += __shfl_down(p0, off, 64);
        p1 += __shfl_down(p1, off, 64);
    }
    if (l == 0) {
        float o0 = p0 + params[768];
        float o1 = p1 + params[769];
        if (flags[0]) {
            ((float*)out)[g * 2 + 0] = o0;
            ((float*)out)[g * 2 + 1] = o1;
        } else {
            ((ushort_t*)out)[g * 2 + 0] = f2bf(o0);
            ((ushort_t*)out)[g * 2 + 1] = f2bf(o1);
        }
    }
}

extern "C" void kernel_launch(void* const* d_in, const int* in_sizes, int n_in,
                              void* d_out, int out_size, void* d_ws, size_t ws_size,
                              hipStream_t stream) {
    const void* x = d_in[0];
    const void* ei = d_in[1];
    const void* batch = d_in[2];
    const void* W1a = d_in[3];
    const void* b1a = d_in[4];
    const void* W1b = d_in[5];
    const void* b1b = d_in[6];
    const void* W2a = d_in[7];
    const void* b2a = d_in[8];
    const void* W2b = d_in[9];
    const void* b2b = d_in[10];
    const void* Wfc = d_in[11];
    const void* bfc = d_in[12];

    // Workspace layout (~36 MB, all chunks 16B-aligned)
    char* base = (char*)d_ws;
    ushort_t* hX = (ushort_t*)base;   base += (size_t)N_NODES * DIM * 2;   // 12.8 MB
    ushort_t* hA = (ushort_t*)base;   base += (size_t)N_NODES * DIM * 2;   // 12.8 MB
    int* src32 = (int*)base;          base += (size_t)N_EDGES * 4;
    int* dst32 = (int*)base;          base += (size_t)N_EDGES * 4;
    int* batch32 = (int*)base;        base += (size_t)N_NODES * 4;
    int* rp = (int*)base;             base += (size_t)(N_NODES + 4) * 4;
    int* cnt = (int*)base;            base += (size_t)N_NODES * 4;
    int* bsum = (int*)base;           base += 256 * 4;
    int* csr = (int*)base;            base += (size_t)N_EDGES * 4;
    ushort_t* wp = (ushort_t*)base;   base += 4 * 16384 * 2;
    float* params = (float*)base;     base += 772 * 4;
    float* gsum = (float*)base;       base += (size_t)NUM_GRAPHS * DIM * 4;  // 256 KB
    int* flags = (int*)base;          base += 16;

    ushort_t* wpA1 = wp;
    ushort_t* wpB1 = wp + 16384;
    ushort_t* wpA2 = wp + 2 * 16384;
    ushort_t* wpB2 = wp + 3 * 16384;

    // Zero hist+gsum, detect dtypes (merged); 256 blocks covers 65536 threads
    zero_detect_kernel<<<256, 256, 0, stream>>>(cnt, gsum, x, ei, flags);
    // Merged canonicalization (x, weights, batch, params)
    prep_kernel<<<PREP_TOTAL, 256, 0, stream>>>(x, batch, W1a, W1b, W2a, W2b,
                                                b1a, b1b, b2a, b2b, Wfc, bfc, flags,
                                                hX, wp, batch32, params);
    conv_edges_hist_kernel<<<(N_EDGES + 255) / 256, 256, 0, stream>>>(ei, flags, src32, dst32, cnt);

    // CSR build
    scan_reduce_kernel<<<SCAN_BLOCKS, 256, 0, stream>>>(cnt, bsum);
    scan_bsum_kernel<<<1, 256, 0, stream>>>(bsum, rp);
    scan_final_kernel<<<SCAN_BLOCKS, 256, 0, stream>>>(cnt, bsum, rp);
    fill_kernel<<<FILL_CHUNKS * FILL_GROUPS, 256, 0, stream>>>(src32, dst32, cnt, csr);

    // Layer 1: agg(hX)->hA, mlp in-place on hA
    agg_kernel<<<(N_NODES + 15) / 16, 256, 0, stream>>>(hX, rp, csr, hA);
    mlp_kernel<<<(N_NODES + 63) / 64, 256, 0, stream>>>(hA, wpA1, params + 0, wpB1, params + 128, hA);
    // Layer 2: agg(hA)->hX, then MLP+pool fused (no h2 global write)
    agg_kernel<<<(N_NODES + 15) / 16, 256, 0, stream>>>(hA, rp, csr, hX);
    mlp_pool_kernel<<<(N_NODES + 63) / 64, 256, 0, stream>>>(hX, wpA2, params + 256, wpB2, params + 384,
                                                             batch32, gsum);
    // Final FC from pooled sums
    fc_kernel<<<NUM_GRAPHS, 64, 0, stream>>>(gsum, batch32, params, flags, d_out);
}